// Round 11
// baseline (1895.446 us; speedup 1.0000x reference)
//
#include <hip/hip_runtime.h>
#include <cstdint>

#define T_DIM 512
#define B_DIM 64
#define I_DIM 256
#define H_DIM 512

typedef _Float16 f16x8 __attribute__((ext_vector_type(8)));
typedef float f32x4  __attribute__((ext_vector_type(4)));
typedef unsigned int u32x4 __attribute__((ext_vector_type(4)));

union H8U { f16x8 v; u32x4 u; };

// ---- ws layout ----
#define WS_FLAGS   0u                          // 8 groups * 1024B; flag(g,j) at g*1024 + j*64
#define WS_STATE   8192u                       // 8 groups * 65536B
#define GRP_U32    16384u                      // per-group: 2 slots x 16 batch x 512 k x 4B
#define WS_XPK     (8192u + 8u*65536u)         // 532480
#define XPK_U32    (512u*4u*8u*64u*4u)         // 16MB
#define WS_NEED_MIN WS_XPK
#define WS_NEED_XPK (WS_XPK + XPK_U32*4u)

__device__ __forceinline__ unsigned short f2h(float f) {
  union { _Float16 h; unsigned short u; } c; c.h = (_Float16)f; return c.u;
}
__device__ __forceinline__ float sigm(float v) { return 1.0f / (1.0f + __expf(-v)); }
__device__ __forceinline__ float tanh_f(float v) {
  float e = __expf(2.0f * fabsf(v));
  float r = 1.0f - 2.0f / (e + 1.0f);
  return copysignf(r, v);
}

// agent-scope coherence-point accesses (PROVEN R2..R10): sc0 sc1
__device__ __forceinline__ void st_u32(unsigned* p, unsigned v) {
  asm volatile("global_store_dword %0, %1, off sc0 sc1" :: "v"(p), "v"(v) : "memory");
}
__device__ __forceinline__ unsigned ld_u32(const unsigned* p) {
  unsigned v;
  asm volatile("global_load_dword %0, %1, off sc0 sc1\n\ts_waitcnt vmcnt(0)"
               : "=v"(v) : "v"(p) : "memory");
  return v;
}

// Zero flags; fill state with tag-5 pattern (value 5 -> c lsb tag=5, never a valid
// expected tag for any slot's FIRST live write -> replay-safe spec detection).
__global__ void __launch_bounds__(256) init_ws_kernel(unsigned* ws) {
  unsigned nf = WS_STATE / 4u;
  unsigned n = WS_XPK / 4u;
  for (unsigned i = blockIdx.x * 256u + threadIdx.x; i < n; i += gridDim.x * 256u)
    __hip_atomic_store(&ws[i], (i < nf) ? 0u : 5u, __ATOMIC_RELAXED, __HIP_MEMORY_SCOPE_AGENT);
}

// pre-pack x into fp16 MFMA fragments: [t][mt(4)][kt(8)][lane(64)] -> 1 dwordx4
__global__ void __launch_bounds__(256) xpack_kernel(const float* __restrict__ x,
                                                    unsigned* __restrict__ xpk) {
  size_t idx = (size_t)blockIdx.x * 256 + threadIdx.x;
  int l = (int)(idx & 63);
  size_t kt = (idx >> 6) & 7, mt = (idx >> 9) & 3, t = idx >> 11;
  const float* xp = x + ((t * 64) + mt * 16 + (size_t)(l & 15)) * 256 + kt * 32 + (size_t)(l >> 4) * 8;
  f32x4 a = *(const f32x4*)xp, b = *(const f32x4*)(xp + 4);
  float v[8] = {a[0], a[1], a[2], a[3], b[0], b[1], b[2], b[3]};
  u32x4 pk;
  #pragma unroll
  for (int i = 0; i < 4; ++i)
    pk[i] = (unsigned)f2h(v[2 * i]) | ((unsigned)f2h(v[2 * i + 1]) << 16);
  *(u32x4*)(xpk + idx * 4) = pk;
}

// 128 blocks x 256 threads (PROVEN). Group g = blockIdx&7, 16 blocks/group, 32 cols/block.
// Speculative state loads BEFORE flag poll; 3-bit step tag in c lsbs verifies freshness;
// stale k-tiles get one guaranteed-fresh reissue (flag observed => stores landed).
template <bool XPK>
__global__ void __launch_bounds__(256, 1) lstm_kernel(
    const float* __restrict__ x, const float* __restrict__ tim,
    const float* __restrict__ Wih_f, const float* __restrict__ Whh_f,
    const float* __restrict__ bias_f, const float* __restrict__ Wd_f,
    const float* __restrict__ bd_f,
    const float* __restrict__ Wih_b, const float* __restrict__ Whh_b,
    const float* __restrict__ bias_b, const float* __restrict__ Wd_b,
    const float* __restrict__ bd_b,
    float* __restrict__ out, char* __restrict__ wsb,
    const unsigned* __restrict__ xpk)
{
  const int tid = threadIdx.x;
  const int w   = tid >> 6;
  const int l   = tid & 63;
  const int lw  = l & 15;
  const int ko  = l >> 4;
  const int g   = blockIdx.x & 7;
  const int js  = blockIdx.x >> 3;        // 0..15
  const int dir = g & 1;
  const int mt  = g >> 1;
  const int b0  = mt * 16;

  const float* Wih  = dir ? Wih_b  : Wih_f;
  const float* Whh  = dir ? Whh_b  : Whh_f;
  const float* bias = dir ? bias_b : bias_f;
  const float* Wd   = dir ? Wd_b   : Wd_f;
  const float* bd   = dir ? bd_b   : bd_f;

  unsigned* flagbase = (unsigned*)(wsb + WS_FLAGS) + (size_t)g * 256;
  unsigned* state = (unsigned*)(wsb + WS_STATE) + (size_t)g * GRP_U32;
  // state u32[slot(2)][batch(16)][k(512)] = (h16<<16) | (c16 & 0xFFF8 | tag3)

  __shared__ float red[4][5][16][34];

  // ---- fp16 weight preload, persists all 512 steps ----
  f16x8 wx[4][2][2];
  f16x8 wh[4][4][2];
  f16x8 wd[4][2];
  #pragma unroll
  for (int xi = 0; xi < 2; ++xi) {
    const int krow = (w * 2 + xi) * 32 + ko * 8;
    #pragma unroll
    for (int g4 = 0; g4 < 4; ++g4) {
      #pragma unroll
      for (int ct = 0; ct < 2; ++ct) {
        const float* p = Wih + (size_t)krow * 2048 + g4 * 512 + js * 32 + ct * 16 + lw;
        #pragma unroll
        for (int i = 0; i < 8; ++i) wx[g4][xi][ct][i] = (_Float16)p[(size_t)i * 2048];
      }
    }
  }
  #pragma unroll
  for (int q = 0; q < 4; ++q) {
    const int krow = w * 128 + q * 32 + ko * 8;
    #pragma unroll
    for (int g4 = 0; g4 < 4; ++g4) {
      #pragma unroll
      for (int ct = 0; ct < 2; ++ct) {
        const float* p = Whh + (size_t)krow * 2048 + g4 * 512 + js * 32 + ct * 16 + lw;
        #pragma unroll
        for (int i = 0; i < 8; ++i) wh[g4][q][ct][i] = (_Float16)p[(size_t)i * 2048];
      }
    }
    #pragma unroll
    for (int ct = 0; ct < 2; ++ct) {
      const float* p2 = Wd + (size_t)krow * 512 + js * 32 + ct * 16 + lw;
      #pragma unroll
      for (int i = 0; i < 8; ++i) wd[q][ct][i] = (_Float16)p2[(size_t)i * 512];
    }
  }

  const int ub = tid >> 4;
  const int uj = tid & 15;
  float bs_i[2], bs_f[2], bs_g[2], bs_o[2], bs_d[2], c_reg[2];
  #pragma unroll
  for (int ct = 0; ct < 2; ++ct) {
    const int jg = js * 32 + ct * 16 + uj;
    bs_i[ct] = bias[jg];
    bs_f[ct] = bias[512 + jg];
    bs_g[ct] = bias[1024 + jg];
    bs_o[ct] = bias[1536 + jg];
    bs_d[ct] = bd[jg];
    c_reg[ct] = 0.0f;
  }

  u32x4 rr[4][2];
  u32x4 xpf0, xpf1;

#define ISSUE_KT(kt) do { \
    const unsigned* sp_ = state + (size_t)lslot * 8192 + (size_t)lw * 512 + w * 128 + (kt) * 32 + ko * 8; \
    asm volatile( \
        "global_load_dwordx4 %0, %2, off sc0 sc1\n\t" \
        "global_load_dwordx4 %1, %2, off offset:16 sc0 sc1" \
        : "=&v"(rr[kt][0]), "=&v"(rr[kt][1]) : "v"(sp_) : "memory"); \
  } while (0)

#define TAGOK(kt) __all((int)( \
    ((rr[kt][0][0] & 7u) == e3) & ((rr[kt][0][1] & 7u) == e3) & \
    ((rr[kt][0][2] & 7u) == e3) & ((rr[kt][0][3] & 7u) == e3) & \
    ((rr[kt][1][0] & 7u) == e3) & ((rr[kt][1][1] & 7u) == e3) & \
    ((rr[kt][1][2] & 7u) == e3) & ((rr[kt][1][3] & 7u) == e3)))

#define MFMA_KT(kt) do { \
    H8U hf_, cf_; \
    hf_.u[0] = __builtin_amdgcn_perm(rr[kt][0][1], rr[kt][0][0], 0x07060302u); \
    hf_.u[1] = __builtin_amdgcn_perm(rr[kt][0][3], rr[kt][0][2], 0x07060302u); \
    hf_.u[2] = __builtin_amdgcn_perm(rr[kt][1][1], rr[kt][1][0], 0x07060302u); \
    hf_.u[3] = __builtin_amdgcn_perm(rr[kt][1][3], rr[kt][1][2], 0x07060302u); \
    cf_.u[0] = __builtin_amdgcn_perm(rr[kt][0][1], rr[kt][0][0], 0x05040100u); \
    cf_.u[1] = __builtin_amdgcn_perm(rr[kt][0][3], rr[kt][0][2], 0x05040100u); \
    cf_.u[2] = __builtin_amdgcn_perm(rr[kt][1][1], rr[kt][1][0], 0x05040100u); \
    cf_.u[3] = __builtin_amdgcn_perm(rr[kt][1][3], rr[kt][1][2], 0x05040100u); \
    _Pragma("unroll") \
    for (int j = 0; j < 4; ++j) cf_.u[j] = (cf_.u[j] & 0xFFF8FFF8u) | 0x00040004u; \
    _Pragma("unroll") \
    for (int g4 = 0; g4 < 4; ++g4) { \
      _Pragma("unroll") \
      for (int ct = 0; ct < 2; ++ct) \
        ag[g4][ct] = __builtin_amdgcn_mfma_f32_16x16x32_f16(hf_.v, wh[g4][kt][ct], ag[g4][ct], 0, 0, 0); \
    } \
    _Pragma("unroll") \
    for (int ct = 0; ct < 2; ++ct) \
      ac[ct] = __builtin_amdgcn_mfma_f32_16x16x32_f16(cf_.v, wd[kt][ct], ac[ct], 0, 0, 0); \
  } while (0)

  // ---- prologue: prefetch x fragments for t=0 ----
  if (XPK) {
    const int ts0 = dir ? (T_DIM - 1) : 0;
    const unsigned* xb = xpk + (((size_t)ts0 * 4 + mt) * 8 + w * 2) * 256 + (size_t)l * 4;
    asm volatile(
        "global_load_dwordx4 %0, %2, off\n\t"
        "global_load_dwordx4 %1, %3, off"
        : "=v"(xpf0), "=v"(xpf1) : "v"(xb), "v"(xb + 256) : "memory");
    asm volatile("s_waitcnt vmcnt(0)" ::: "memory");
    __builtin_amdgcn_sched_barrier(0);
  }

  for (int t = 0; t < T_DIM; ++t) {
    const int tsrc = dir ? (T_DIM - 1 - t) : t;
    const int sslot = t & 1;
    const int lslot = sslot ^ 1;

    float tt = tim[(size_t)tsrc * B_DIM + b0 + ub];

    f16x8 ax[2];
    if (XPK) {
      H8U u0, u1; u0.u = xpf0; u1.u = xpf1;
      ax[0] = u0.v; ax[1] = u1.v;
    } else {
      #pragma unroll
      for (int xi = 0; xi < 2; ++xi) {
        const float* xp = x + ((size_t)tsrc * B_DIM + b0 + lw) * I_DIM + (w * 2 + xi) * 32 + ko * 8;
        f32x4 v0 = *(const f32x4*)xp;
        f32x4 v1 = *(const f32x4*)(xp + 4);
        f16x8 vv;
        #pragma unroll
        for (int i = 0; i < 4; ++i) { vv[i] = (_Float16)v0[i]; vv[4 + i] = (_Float16)v1[i]; }
        ax[xi] = vv;
      }
    }

    // ---- S1: SPECULATIVE state loads (before poll!) + next-x prefetch ----
    if (t > 0) { ISSUE_KT(0); ISSUE_KT(1); ISSUE_KT(2); ISSUE_KT(3); }
    if (XPK) {
      const int tn = (t + 1 < T_DIM) ? (dir ? (T_DIM - 2 - t) : (t + 1)) : 0;
      const unsigned* xbn = xpk + (((size_t)tn * 4 + mt) * 8 + w * 2) * 256 + (size_t)l * 4;
      asm volatile(
          "global_load_dwordx4 %0, %2, off\n\t"
          "global_load_dwordx4 %1, %3, off"
          : "=v"(xpf0), "=v"(xpf1) : "v"(xbn), "v"(xbn + 256) : "memory");
    }

    // ---- X MFMAs (overlap spec-load flight) ----
    f32x4 ag[4][2]; f32x4 ac[2];
    #pragma unroll
    for (int g4 = 0; g4 < 4; ++g4) { ag[g4][0] = (f32x4)0.0f; ag[g4][1] = (f32x4)0.0f; }
    ac[0] = (f32x4)0.0f; ac[1] = (f32x4)0.0f;
    #pragma unroll
    for (int xi = 0; xi < 2; ++xi) {
      #pragma unroll
      for (int g4 = 0; g4 < 4; ++g4) {
        #pragma unroll
        for (int ct = 0; ct < 2; ++ct)
          ag[g4][ct] = __builtin_amdgcn_mfma_f32_16x16x32_f16(ax[xi], wx[g4][xi][ct], ag[g4][ct], 0, 0, 0);
      }
    }

    if (t > 0) {
      // ---- W0: poll flags (vmcnt(0) inside also drains spec loads in parallel) ----
      if (l < 16) {
        const unsigned* fl = flagbase + (size_t)l * 16;
        while (ld_u32(fl) < (unsigned)t) { }
      }
      asm volatile("s_waitcnt vmcnt(0)" ::: "memory");   // lanes>=16: ensure spec data readable
      __builtin_amdgcn_sched_barrier(0);

      // ---- tag verify; stale k-tiles -> one guaranteed-fresh reissue ----
      const unsigned e3 = (((unsigned)(t - 1)) >> 1) & 7u;
      int f0 = !TAGOK(0), f1 = !TAGOK(1), f2 = !TAGOK(2), f3 = !TAGOK(3);
      while (f0 | f1 | f2 | f3) {
        if (f0) ISSUE_KT(0);
        if (f1) ISSUE_KT(1);
        if (f2) ISSUE_KT(2);
        if (f3) ISSUE_KT(3);
        asm volatile("s_waitcnt vmcnt(0)" ::: "memory");
        __builtin_amdgcn_sched_barrier(0);
        if (f0) f0 = !TAGOK(0);
        if (f1) f1 = !TAGOK(1);
        if (f2) f2 = !TAGOK(2);
        if (f3) f3 = !TAGOK(3);
      }

      MFMA_KT(0); MFMA_KT(1); MFMA_KT(2); MFMA_KT(3);
    }

    // ---- S2b: cross-wave reduce via LDS; raw lgkm barrier ----
    #pragma unroll
    for (int g4 = 0; g4 < 4; ++g4) {
      #pragma unroll
      for (int ct = 0; ct < 2; ++ct) {
        f32x4 s = ag[g4][ct];
        #pragma unroll
        for (int r = 0; r < 4; ++r) red[w][g4][ko * 4 + r][ct * 16 + lw] = s[r];
      }
    }
    #pragma unroll
    for (int ct = 0; ct < 2; ++ct) {
      f32x4 s = ac[ct];
      #pragma unroll
      for (int r = 0; r < 4; ++r) red[w][4][ko * 4 + r][ct * 16 + lw] = s[r];
    }
    asm volatile("s_waitcnt lgkmcnt(0)" ::: "memory");
    __builtin_amdgcn_s_barrier();

    // ---- S3: update + tagged state stores (out deferred past flag) ----
    const float dinv = 1.0f / __logf(2.718281828459045f + tt);
    const unsigned ptag = (((unsigned)t) >> 1) & 7u;
    float h_keep[2];
    #pragma unroll
    for (int ct = 0; ct < 2; ++ct) {
      const int cj = ct * 16 + uj;
      float gi = red[0][0][ub][cj] + red[1][0][ub][cj] + red[2][0][ub][cj] + red[3][0][ub][cj] + bs_i[ct];
      float gf = red[0][1][ub][cj] + red[1][1][ub][cj] + red[2][1][ub][cj] + red[3][1][ub][cj] + bs_f[ct];
      float gg = red[0][2][ub][cj] + red[1][2][ub][cj] + red[2][2][ub][cj] + red[3][2][ub][cj] + bs_g[ct];
      float go = red[0][3][ub][cj] + red[1][3][ub][cj] + red[2][3][ub][cj] + red[3][3][ub][cj] + bs_o[ct];
      float csv = red[0][4][ub][cj] + red[1][4][ub][cj] + red[2][4][ub][cj] + red[3][4][ub][cj] + bs_d[ct];

      float c_s = tanh_f(csv);
      float c_adj = c_reg[ct] - c_s + c_s * dinv;
      float iv = sigm(gi);
      float fv = sigm(gf);
      float ov = sigm(go);
      float gv = tanh_f(gg);
      float c_new = fv * c_adj + iv * gv;
      float h_new = ov * tanh_f(c_new);
      c_reg[ct] = c_new;
      h_keep[ct] = h_new;

      const int jglob = js * 32 + cj;
      unsigned ch = ((unsigned)f2h(c_new) & 0xFFF8u) | ptag;
      unsigned val = ((unsigned)f2h(h_new) << 16) | ch;
      st_u32(state + (size_t)sslot * 8192 + (size_t)ub * 512 + jglob, val);
    }

    // ---- S4: drain state stores only, barrier, flag, THEN out stores ----
    asm volatile("s_waitcnt vmcnt(0)" ::: "memory");
    __syncthreads();
    if (tid == 0) st_u32(flagbase + (size_t)js * 16, (unsigned)(t + 1));
    #pragma unroll
    for (int ct = 0; ct < 2; ++ct)
      out[((size_t)tsrc * B_DIM + b0 + ub) * 1024 + dir * 512 + js * 32 + ct * 16 + uj] = h_keep[ct];
  }
#undef ISSUE_KT
#undef TAGOK
#undef MFMA_KT
}

extern "C" void kernel_launch(void* const* d_in, const int* in_sizes, int n_in,
                              void* d_out, int out_size, void* d_ws, size_t ws_size,
                              hipStream_t stream) {
  (void)in_sizes; (void)n_in; (void)out_size;
  if (ws_size < (size_t)WS_NEED_MIN) return;  // failure signature: ws too small
  const bool use_xpk = ws_size >= (size_t)WS_NEED_XPK;

  const float* x     = (const float*)d_in[0];
  const float* tim   = (const float*)d_in[1];
  const float* Wih_f = (const float*)d_in[2];
  const float* Whh_f = (const float*)d_in[3];
  const float* b_f   = (const float*)d_in[4];
  const float* Wd_f  = (const float*)d_in[5];
  const float* bd_f  = (const float*)d_in[6];
  const float* Wih_b = (const float*)d_in[7];
  const float* Whh_b = (const float*)d_in[8];
  const float* b_b   = (const float*)d_in[9];
  const float* Wd_b  = (const float*)d_in[10];
  const float* bd_b  = (const float*)d_in[11];
  float* out = (float*)d_out;
  char* ws = (char*)d_ws;
  unsigned* xpk = (unsigned*)(ws + WS_XPK);

  hipLaunchKernelGGL(init_ws_kernel, dim3(64), dim3(256), 0, stream, (unsigned*)ws);
  if (use_xpk) {
    hipLaunchKernelGGL(xpack_kernel, dim3(4096), dim3(256), 0, stream, x, xpk);
    hipLaunchKernelGGL((lstm_kernel<true>), dim3(128), dim3(256), 0, stream,
                       x, tim, Wih_f, Whh_f, b_f, Wd_f, bd_f,
                       Wih_b, Whh_b, b_b, Wd_b, bd_b, out, ws, xpk);
  } else {
    hipLaunchKernelGGL((lstm_kernel<false>), dim3(128), dim3(256), 0, stream,
                       x, tim, Wih_f, Whh_f, b_f, Wd_f, bd_f,
                       Wih_b, Whh_b, b_b, Wd_b, bd_b, out, ws, (const unsigned*)nullptr);
  }
}

// Round 12
// 1684.607 us; speedup vs baseline: 1.1252x; 1.1252x over previous
//
#include <hip/hip_runtime.h>
#include <cstdint>

#define T_DIM 512
#define B_DIM 64
#define I_DIM 256
#define H_DIM 512

typedef _Float16 f16x8 __attribute__((ext_vector_type(8)));
typedef float f32x4  __attribute__((ext_vector_type(4)));
typedef unsigned int u32x4 __attribute__((ext_vector_type(4)));

union H8U { f16x8 v; u32x4 u; };

// ---- ws layout ----
#define WS_FLAGS   0u                          // 8 groups * 4096B; flag(g, js, wp) 64B-strided
#define WS_STATE   32768u                      // 8 groups * 65536B
#define GRP_U32    16384u                      // per-group: 2 slots x 16 batch x 512 k x 4B
#define WS_XPK     (32768u + 8u*65536u)        // 557056
#define XPK_U32    (512u*4u*8u*64u*4u)         // 16MB
#define WS_NEED_MIN WS_XPK
#define WS_NEED_XPK (WS_XPK + XPK_U32*4u)

__device__ __forceinline__ unsigned short f2h(float f) {
  union { _Float16 h; unsigned short u; } c; c.h = (_Float16)f; return c.u;
}
__device__ __forceinline__ float sigm(float v) { return 1.0f / (1.0f + __expf(-v)); }
__device__ __forceinline__ float tanh_f(float v) {
  float e = __expf(2.0f * fabsf(v));
  float r = 1.0f - 2.0f / (e + 1.0f);
  return copysignf(r, v);
}

// agent-scope coherence-point accesses (PROVEN R2..R10): sc0 sc1
__device__ __forceinline__ void st_u32(unsigned* p, unsigned v) {
  asm volatile("global_store_dword %0, %1, off sc0 sc1" :: "v"(p), "v"(v) : "memory");
}
__device__ __forceinline__ unsigned ld_u32(const unsigned* p) {
  unsigned v;
  asm volatile("global_load_dword %0, %1, off sc0 sc1\n\ts_waitcnt vmcnt(0)"
               : "=v"(v) : "v"(p) : "memory");
  return v;
}

__global__ void __launch_bounds__(256) init_ws_kernel(unsigned* ws) {
  unsigned n = WS_FLAGS + 32768u / 4u;         // zero flags region only
  for (unsigned i = blockIdx.x * 256u + threadIdx.x; i < n; i += gridDim.x * 256u)
    __hip_atomic_store(&ws[i], 0u, __ATOMIC_RELAXED, __HIP_MEMORY_SCOPE_AGENT);
}

// pre-pack x into fp16 MFMA fragments: [t][mt(4)][kt(8)][lane(64)] -> 1 dwordx4
__global__ void __launch_bounds__(256) xpack_kernel(const float* __restrict__ x,
                                                    unsigned* __restrict__ xpk) {
  size_t idx = (size_t)blockIdx.x * 256 + threadIdx.x;
  int l = (int)(idx & 63);
  size_t kt = (idx >> 6) & 7, mt = (idx >> 9) & 3, t = idx >> 11;
  const float* xp = x + ((t * 64) + mt * 16 + (size_t)(l & 15)) * 256 + kt * 32 + (size_t)(l >> 4) * 8;
  f32x4 a = *(const f32x4*)xp, b = *(const f32x4*)(xp + 4);
  float v[8] = {a[0], a[1], a[2], a[3], b[0], b[1], b[2], b[3]};
  u32x4 pk;
  #pragma unroll
  for (int i = 0; i < 4; ++i)
    pk[i] = (unsigned)f2h(v[2 * i]) | ((unsigned)f2h(v[2 * i + 1]) << 16);
  *(u32x4*)(xpk + idx * 4) = pk;
}

// 128 blocks x 256 threads. Group g = blockIdx&7, 16 blocks/group, 32 cols/block.
// PER-(block,wave) flags: producer wave wp covers batches [4wp,4wp+4) of its block's
// 32 cols; drains ITS OWN stores (vmcnt is per-wave) and releases its own flag — no
// block barrier on the release path. Consumer wave w depends only on blocks
// 4w..4w+3 (16 flags), polled by lanes 0..15.
template <bool XPK>
__global__ void __launch_bounds__(256, 1) lstm_kernel(
    const float* __restrict__ x, const float* __restrict__ tim,
    const float* __restrict__ Wih_f, const float* __restrict__ Whh_f,
    const float* __restrict__ bias_f, const float* __restrict__ Wd_f,
    const float* __restrict__ bd_f,
    const float* __restrict__ Wih_b, const float* __restrict__ Whh_b,
    const float* __restrict__ bias_b, const float* __restrict__ Wd_b,
    const float* __restrict__ bd_b,
    float* __restrict__ out, char* __restrict__ wsb,
    const unsigned* __restrict__ xpk)
{
  const int tid = threadIdx.x;
  const int w   = tid >> 6;
  const int l   = tid & 63;
  const int lw  = l & 15;
  const int ko  = l >> 4;
  const int g   = blockIdx.x & 7;
  const int js  = blockIdx.x >> 3;        // 0..15
  const int dir = g & 1;
  const int mt  = g >> 1;
  const int b0  = mt * 16;

  const float* Wih  = dir ? Wih_b  : Wih_f;
  const float* Whh  = dir ? Whh_b  : Whh_f;
  const float* bias = dir ? bias_b : bias_f;
  const float* Wd   = dir ? Wd_b   : Wd_f;
  const float* bd   = dir ? bd_b   : bd_f;

  unsigned* flagbase = (unsigned*)(wsb + WS_FLAGS) + (size_t)g * 1024;  // 4KB/group
  unsigned* state = (unsigned*)(wsb + WS_STATE) + (size_t)g * GRP_U32;
  // state u32[slot(2)][batch(16)][k(512)] = (h16<<16)|c16

  __shared__ float red[4][5][16][34];     // 43.5KB

  // ---- fp16 weight preload, persists all 512 steps ----
  f16x8 wx[4][2][2];
  f16x8 wh[4][4][2];
  f16x8 wd[4][2];
  #pragma unroll
  for (int xi = 0; xi < 2; ++xi) {
    const int krow = (w * 2 + xi) * 32 + ko * 8;
    #pragma unroll
    for (int g4 = 0; g4 < 4; ++g4) {
      #pragma unroll
      for (int ct = 0; ct < 2; ++ct) {
        const float* p = Wih + (size_t)krow * 2048 + g4 * 512 + js * 32 + ct * 16 + lw;
        #pragma unroll
        for (int i = 0; i < 8; ++i) wx[g4][xi][ct][i] = (_Float16)p[(size_t)i * 2048];
      }
    }
  }
  #pragma unroll
  for (int q = 0; q < 4; ++q) {
    const int krow = w * 128 + q * 32 + ko * 8;
    #pragma unroll
    for (int g4 = 0; g4 < 4; ++g4) {
      #pragma unroll
      for (int ct = 0; ct < 2; ++ct) {
        const float* p = Whh + (size_t)krow * 2048 + g4 * 512 + js * 32 + ct * 16 + lw;
        #pragma unroll
        for (int i = 0; i < 8; ++i) wh[g4][q][ct][i] = (_Float16)p[(size_t)i * 2048];
      }
    }
    #pragma unroll
    for (int ct = 0; ct < 2; ++ct) {
      const float* p2 = Wd + (size_t)krow * 512 + js * 32 + ct * 16 + lw;
      #pragma unroll
      for (int i = 0; i < 8; ++i) wd[q][ct][i] = (_Float16)p2[(size_t)i * 512];
    }
  }

  const int ub = tid >> 4;
  const int uj = tid & 15;
  float bs_i[2], bs_f[2], bs_g[2], bs_o[2], bs_d[2], c_reg[2];
  #pragma unroll
  for (int ct = 0; ct < 2; ++ct) {
    const int jg = js * 32 + ct * 16 + uj;
    bs_i[ct] = bias[jg];
    bs_f[ct] = bias[512 + jg];
    bs_g[ct] = bias[1024 + jg];
    bs_o[ct] = bias[1536 + jg];
    bs_d[ct] = bd[jg];
    c_reg[ct] = 0.0f;
  }

  // consumer poll target for lanes 0..15: block 4w + (l>>2), wave l&3
  const unsigned* myflag = flagbase + (size_t)((4 * w + (l >> 2)) * 4 + (l & 3)) * 16;
  // producer release flag for this (block, wave): lane 0 stores it
  unsigned* relflag = flagbase + (size_t)(js * 4 + w) * 16;

  u32x4 rr[4][2];
  u32x4 xpf0, xpf1;

#define ISSUE_KT(kt) do { \
    const unsigned* sp_ = state + (size_t)lslot * 8192 + (size_t)lw * 512 + w * 128 + (kt) * 32 + ko * 8; \
    asm volatile( \
        "global_load_dwordx4 %0, %2, off sc0 sc1\n\t" \
        "global_load_dwordx4 %1, %2, off offset:16 sc0 sc1" \
        : "=&v"(rr[kt][0]), "=&v"(rr[kt][1]) : "v"(sp_) : "memory"); \
  } while (0)

#define MFMA_KT(kt) do { \
    H8U hf_, cf_; \
    hf_.u[0] = __builtin_amdgcn_perm(rr[kt][0][1], rr[kt][0][0], 0x07060302u); \
    hf_.u[1] = __builtin_amdgcn_perm(rr[kt][0][3], rr[kt][0][2], 0x07060302u); \
    hf_.u[2] = __builtin_amdgcn_perm(rr[kt][1][1], rr[kt][1][0], 0x07060302u); \
    hf_.u[3] = __builtin_amdgcn_perm(rr[kt][1][3], rr[kt][1][2], 0x07060302u); \
    cf_.u[0] = __builtin_amdgcn_perm(rr[kt][0][1], rr[kt][0][0], 0x05040100u); \
    cf_.u[1] = __builtin_amdgcn_perm(rr[kt][0][3], rr[kt][0][2], 0x05040100u); \
    cf_.u[2] = __builtin_amdgcn_perm(rr[kt][1][1], rr[kt][1][0], 0x05040100u); \
    cf_.u[3] = __builtin_amdgcn_perm(rr[kt][1][3], rr[kt][1][2], 0x05040100u); \
    _Pragma("unroll") \
    for (int g4 = 0; g4 < 4; ++g4) { \
      _Pragma("unroll") \
      for (int ct = 0; ct < 2; ++ct) \
        ag[g4][ct] = __builtin_amdgcn_mfma_f32_16x16x32_f16(hf_.v, wh[g4][kt][ct], ag[g4][ct], 0, 0, 0); \
    } \
    _Pragma("unroll") \
    for (int ct = 0; ct < 2; ++ct) \
      ac[ct] = __builtin_amdgcn_mfma_f32_16x16x32_f16(cf_.v, wd[kt][ct], ac[ct], 0, 0, 0); \
  } while (0)

  // ---- prologue: prefetch x fragments for t=0 ----
  if (XPK) {
    const int ts0 = dir ? (T_DIM - 1) : 0;
    const unsigned* xb = xpk + (((size_t)ts0 * 4 + mt) * 8 + w * 2) * 256 + (size_t)l * 4;
    asm volatile(
        "global_load_dwordx4 %0, %2, off\n\t"
        "global_load_dwordx4 %1, %3, off"
        : "=v"(xpf0), "=v"(xpf1) : "v"(xb), "v"(xb + 256) : "memory");
    asm volatile("s_waitcnt vmcnt(0)" ::: "memory");
    __builtin_amdgcn_sched_barrier(0);
  }

  for (int t = 0; t < T_DIM; ++t) {
    const int tsrc = dir ? (T_DIM - 1 - t) : t;
    const int sslot = t & 1;
    const int lslot = sslot ^ 1;

    float tt = tim[(size_t)tsrc * B_DIM + b0 + ub];

    f16x8 ax[2];
    if (XPK) {
      H8U u0, u1; u0.u = xpf0; u1.u = xpf1;
      ax[0] = u0.v; ax[1] = u1.v;
    } else {
      #pragma unroll
      for (int xi = 0; xi < 2; ++xi) {
        const float* xp = x + ((size_t)tsrc * B_DIM + b0 + lw) * I_DIM + (w * 2 + xi) * 32 + ko * 8;
        f32x4 v0 = *(const f32x4*)xp;
        f32x4 v1 = *(const f32x4*)(xp + 4);
        f16x8 vv;
        #pragma unroll
        for (int i = 0; i < 4; ++i) { vv[i] = (_Float16)v0[i]; vv[4 + i] = (_Float16)v1[i]; }
        ax[xi] = vv;
      }
    }

    // ---- X MFMAs (independent of t-1) ----
    f32x4 ag[4][2]; f32x4 ac[2];
    #pragma unroll
    for (int g4 = 0; g4 < 4; ++g4) { ag[g4][0] = (f32x4)0.0f; ag[g4][1] = (f32x4)0.0f; }
    ac[0] = (f32x4)0.0f; ac[1] = (f32x4)0.0f;
    #pragma unroll
    for (int xi = 0; xi < 2; ++xi) {
      #pragma unroll
      for (int g4 = 0; g4 < 4; ++g4) {
        #pragma unroll
        for (int ct = 0; ct < 2; ++ct)
          ag[g4][ct] = __builtin_amdgcn_mfma_f32_16x16x32_f16(ax[xi], wx[g4][xi][ct], ag[g4][ct], 0, 0, 0);
      }
    }

    if (t > 0) {
      // ---- W0: poll ONLY this wave's 16 source flags (4 blocks x 4 waves) ----
      if (l < 16) {
        while (ld_u32(myflag) < (unsigned)t) { }
      }
      __builtin_amdgcn_sched_barrier(0);

      // ---- S1: issue loads + next-x prefetch; counted overlap ----
      ISSUE_KT(0); ISSUE_KT(1); ISSUE_KT(2); ISSUE_KT(3);
      if (XPK) {
        const int tn = (t + 1 < T_DIM) ? (dir ? (T_DIM - 2 - t) : (t + 1)) : 0;
        const unsigned* xbn = xpk + (((size_t)tn * 4 + mt) * 8 + w * 2) * 256 + (size_t)l * 4;
        asm volatile(
            "global_load_dwordx4 %0, %2, off\n\t"
            "global_load_dwordx4 %1, %3, off"
            : "=v"(xpf0), "=v"(xpf1) : "v"(xbn), "v"(xbn + 256) : "memory");
      }

      if (XPK) { asm volatile("s_waitcnt vmcnt(8)" ::: "memory"); }
      else     { asm volatile("s_waitcnt vmcnt(6)" ::: "memory"); }
      __builtin_amdgcn_sched_barrier(0);
      MFMA_KT(0);
      if (XPK) { asm volatile("s_waitcnt vmcnt(6)" ::: "memory"); }
      else     { asm volatile("s_waitcnt vmcnt(4)" ::: "memory"); }
      __builtin_amdgcn_sched_barrier(0);
      MFMA_KT(1);
      if (XPK) { asm volatile("s_waitcnt vmcnt(4)" ::: "memory"); }
      else     { asm volatile("s_waitcnt vmcnt(2)" ::: "memory"); }
      __builtin_amdgcn_sched_barrier(0);
      MFMA_KT(2);
      if (XPK) { asm volatile("s_waitcnt vmcnt(2)" ::: "memory"); }
      else     { asm volatile("s_waitcnt vmcnt(0)" ::: "memory"); }
      __builtin_amdgcn_sched_barrier(0);
      MFMA_KT(3);
    } else if (XPK) {
      const int tn = dir ? (T_DIM - 2) : 1;
      const unsigned* xbn = xpk + (((size_t)tn * 4 + mt) * 8 + w * 2) * 256 + (size_t)l * 4;
      asm volatile(
          "global_load_dwordx4 %0, %2, off\n\t"
          "global_load_dwordx4 %1, %3, off"
          : "=v"(xpf0), "=v"(xpf1) : "v"(xbn), "v"(xbn + 256) : "memory");
    }

    // ---- S2b: cross-wave reduce via LDS; barrier A ----
    #pragma unroll
    for (int g4 = 0; g4 < 4; ++g4) {
      #pragma unroll
      for (int ct = 0; ct < 2; ++ct) {
        f32x4 s = ag[g4][ct];
        #pragma unroll
        for (int r = 0; r < 4; ++r) red[w][g4][ko * 4 + r][ct * 16 + lw] = s[r];
      }
    }
    #pragma unroll
    for (int ct = 0; ct < 2; ++ct) {
      f32x4 s = ac[ct];
      #pragma unroll
      for (int r = 0; r < 4; ++r) red[w][4][ko * 4 + r][ct * 16 + lw] = s[r];
    }
    asm volatile("s_waitcnt lgkmcnt(0)" ::: "memory");
    __builtin_amdgcn_s_barrier();

    // ---- S3: update + state stores; PER-WAVE drain + PER-WAVE flag release ----
    const float dinv = 1.0f / __logf(2.718281828459045f + tt);
    float h_keep[2];
    #pragma unroll
    for (int ct = 0; ct < 2; ++ct) {
      const int cj = ct * 16 + uj;
      float gi = red[0][0][ub][cj] + red[1][0][ub][cj] + red[2][0][ub][cj] + red[3][0][ub][cj] + bs_i[ct];
      float gf = red[0][1][ub][cj] + red[1][1][ub][cj] + red[2][1][ub][cj] + red[3][1][ub][cj] + bs_f[ct];
      float gg = red[0][2][ub][cj] + red[1][2][ub][cj] + red[2][2][ub][cj] + red[3][2][ub][cj] + bs_g[ct];
      float go = red[0][3][ub][cj] + red[1][3][ub][cj] + red[2][3][ub][cj] + red[3][3][ub][cj] + bs_o[ct];
      float csv = red[0][4][ub][cj] + red[1][4][ub][cj] + red[2][4][ub][cj] + red[3][4][ub][cj] + bs_d[ct];

      float c_s = tanh_f(csv);
      float c_adj = c_reg[ct] - c_s + c_s * dinv;
      float iv = sigm(gi);
      float fv = sigm(gf);
      float ov = sigm(go);
      float gv = tanh_f(gg);
      float c_new = fv * c_adj + iv * gv;
      float h_new = ov * tanh_f(c_new);
      c_reg[ct] = c_new;
      h_keep[ct] = h_new;

      const int jglob = js * 32 + cj;
      unsigned val = ((unsigned)f2h(h_new) << 16) | (unsigned)f2h(c_new);
      st_u32(state + (size_t)sslot * 8192 + (size_t)ub * 512 + jglob, val);
    }

    // per-wave: drain own stores (incl. this step's xpf), release own flag
    asm volatile("s_waitcnt vmcnt(0)" ::: "memory");
    __builtin_amdgcn_sched_barrier(0);
    if (l == 0) st_u32(relflag, (unsigned)(t + 1));

    // out stores (off the release path)
    #pragma unroll
    for (int ct = 0; ct < 2; ++ct)
      out[((size_t)tsrc * B_DIM + b0 + ub) * 1024 + dir * 512 + js * 32 + ct * 16 + uj] = h_keep[ct];

    // barrier B: guard red[] reuse (after flag release -> off critical path)
    __builtin_amdgcn_s_barrier();
  }
#undef ISSUE_KT
#undef MFMA_KT
}

extern "C" void kernel_launch(void* const* d_in, const int* in_sizes, int n_in,
                              void* d_out, int out_size, void* d_ws, size_t ws_size,
                              hipStream_t stream) {
  (void)in_sizes; (void)n_in; (void)out_size;
  if (ws_size < (size_t)WS_NEED_MIN) return;  // failure signature: ws too small
  const bool use_xpk = ws_size >= (size_t)WS_NEED_XPK;

  const float* x     = (const float*)d_in[0];
  const float* tim   = (const float*)d_in[1];
  const float* Wih_f = (const float*)d_in[2];
  const float* Whh_f = (const float*)d_in[3];
  const float* b_f   = (const float*)d_in[4];
  const float* Wd_f  = (const float*)d_in[5];
  const float* bd_f  = (const float*)d_in[6];
  const float* Wih_b = (const float*)d_in[7];
  const float* Whh_b = (const float*)d_in[8];
  const float* b_b   = (const float*)d_in[9];
  const float* Wd_b  = (const float*)d_in[10];
  const float* bd_b  = (const float*)d_in[11];
  float* out = (float*)d_out;
  char* ws = (char*)d_ws;
  unsigned* xpk = (unsigned*)(ws + WS_XPK);

  hipLaunchKernelGGL(init_ws_kernel, dim3(8), dim3(256), 0, stream, (unsigned*)ws);
  if (use_xpk) {
    hipLaunchKernelGGL(xpack_kernel, dim3(4096), dim3(256), 0, stream, x, xpk);
    hipLaunchKernelGGL((lstm_kernel<true>), dim3(128), dim3(256), 0, stream,
                       x, tim, Wih_f, Whh_f, b_f, Wd_f, bd_f,
                       Wih_b, Whh_b, b_b, Wd_b, bd_b, out, ws, xpk);
  } else {
    hipLaunchKernelGGL((lstm_kernel<false>), dim3(128), dim3(256), 0, stream,
                       x, tim, Wih_f, Whh_f, b_f, Wd_f, bd_f,
                       Wih_b, Whh_b, b_b, Wd_b, bd_b, out, ws, (const unsigned*)nullptr);
  }
}